// Round 1
// baseline (2053.754 us; speedup 1.0000x reference)
//
#include <hip/hip_runtime.h>
#include <math.h>

#define TEMP 0.0005f
#define B_    32
#define CMEL  80
#define CTXT  512
#define T1_   1600
#define T2_   400

// ---------------- speaker-embed bias vectors ----------------
// kb[b,c] = bks[c] + se[b,:] . Wks[c,:]   (c < 512)
// qb[b,c] = bqs[c] + se[b,:] . Wqs[c,:]   (c < 80)
__global__ void bias_kernel(const float* __restrict__ se,
                            const float* __restrict__ Wks, const float* __restrict__ bks,
                            const float* __restrict__ Wqs, const float* __restrict__ bqs,
                            float* __restrict__ kb, float* __restrict__ qb) {
    int tid = blockIdx.x * blockDim.x + threadIdx.x;
    const int nk = B_ * CTXT;
    if (tid < nk) {
        int b = tid / CTXT, c = tid % CTXT;
        const float4* s4 = reinterpret_cast<const float4*>(se + b * CTXT);
        const float4* w4 = reinterpret_cast<const float4*>(Wks + (size_t)c * CTXT);
        float acc = bks[c];
        #pragma unroll 4
        for (int j = 0; j < CTXT / 4; ++j) {
            float4 a = s4[j], w = w4[j];
            acc += a.x * w.x + a.y * w.y + a.z * w.z + a.w * w.w;
        }
        kb[tid] = acc;
    } else if (tid < nk + B_ * CMEL) {
        int t = tid - nk;
        int b = t / CMEL, c = t % CMEL;
        const float4* s4 = reinterpret_cast<const float4*>(se + b * CTXT);
        const float4* w4 = reinterpret_cast<const float4*>(Wqs + (size_t)c * CTXT);
        float acc = bqs[c];
        #pragma unroll 4
        for (int j = 0; j < CTXT / 4; ++j) {
            float4 a = s4[j], w = w4[j];
            acc += a.x * w.x + a.y * w.y + a.z * w.z + a.w * w.w;
        }
        qb[t] = acc;
    }
}

// ---------------- generic conv1d (kernel size KS in {1,3}) ----------------
// out[b,co,t] = bias[co] + sum_{ci,dt} W[co,ci,dt] * (in[b,ci,t+dt-PAD] (+inBias[b,ci]))
// Tile: 32 co x 128 t per block, 256 threads, each thread 4co x 4t.
template<int KS, bool RELU, bool INBIAS>
__global__ __launch_bounds__(256) void conv_kernel(
        const float* __restrict__ in, const float* __restrict__ W,
        const float* __restrict__ bias, const float* __restrict__ inBias,
        float* __restrict__ out, int Cout, int Cin, int T) {
    constexpr int PAD = (KS - 1) / 2;
    constexpr int WIDTH = 128 + KS - 1;
    __shared__ float Xs[8][WIDTH];
    __shared__ float Ws[32][8 * KS];
    const int b = blockIdx.z;
    const int co0 = blockIdx.y * 32;
    const int t0 = blockIdx.x * 128;
    const int tid = threadIdx.x;
    const int tt = tid & 31;   // t within tile
    const int tc = tid >> 5;   // co group (0..7)
    float acc[4][4] = {};

    for (int ci0 = 0; ci0 < Cin; ci0 += 8) {
        // stage X tile (with halo, zero padding, optional per-(b,ci) bias)
        {
            const int row = tc;  // 0..7
            const float* src = in + ((size_t)b * Cin + ci0 + row) * T;
            float ib = 0.f;
            if (INBIAS) ib = inBias[b * Cin + ci0 + row];
            for (int l = tt; l < WIDTH; l += 32) {
                int t = t0 - PAD + l;
                float v = 0.f;
                if (t >= 0 && t < T) v = src[t] + ib;
                Xs[row][l] = v;
            }
        }
        // stage W tile
        for (int idx = tid; idx < 32 * 8 * KS; idx += 256) {
            int row = idx / (8 * KS);
            int col = idx - row * (8 * KS);
            int co = co0 + row;
            float v = 0.f;
            if (co < Cout) v = W[((size_t)co * Cin + ci0) * KS + col];
            Ws[row][col] = v;
        }
        __syncthreads();
        #pragma unroll
        for (int ci = 0; ci < 8; ++ci) {
            #pragma unroll
            for (int dt = 0; dt < KS; ++dt) {
                float xv[4], wv[4];
                #pragma unroll
                for (int j = 0; j < 4; ++j) xv[j] = Xs[ci][tt + 32 * j + dt];
                #pragma unroll
                for (int i = 0; i < 4; ++i) wv[i] = Ws[tc + 8 * i][ci * KS + dt];
                #pragma unroll
                for (int i = 0; i < 4; ++i)
                    #pragma unroll
                    for (int j = 0; j < 4; ++j)
                        acc[i][j] += wv[i] * xv[j];
            }
        }
        __syncthreads();
    }
    #pragma unroll
    for (int i = 0; i < 4; ++i) {
        int co = co0 + tc + 8 * i;
        if (co >= Cout) continue;
        float bv = bias[co];
        #pragma unroll
        for (int j = 0; j < 4; ++j) {
            int t = t0 + tt + 32 * j;
            if (t >= T) continue;
            float v = acc[i][j] + bv;
            if (RELU) v = fmaxf(v, 0.f);
            out[((size_t)b * Cout + co) * T + t] = v;
        }
    }
}

// ---------------- channel sum-of-squares ----------------
__global__ void sqsum_kernel(const float* __restrict__ x, float* __restrict__ out,
                             int C, int T) {
    int b = blockIdx.y;
    int t = blockIdx.x * 256 + threadIdx.x;
    if (t >= T) return;
    const float* p = x + (size_t)b * C * T + t;
    float acc = 0.f;
    #pragma unroll 4
    for (int c = 0; c < 80; ++c) { float v = p[(size_t)c * T]; acc += v * v; }
    out[b * T + t] = acc;
}

// ---------------- fused qk GEMM + log_softmax + prior + masked softmax ----------------
// Block: 16 rows (t1) x full 400 cols (t2). 256 threads = 4 waves; wave w owns rows 4w..4w+3.
__global__ __launch_bounds__(256) void attn_kernel(
        const float* __restrict__ qf, const float* __restrict__ kf,
        const float* __restrict__ q2s, const float* __restrict__ k2s,
        const int* __restrict__ mask, const float* __restrict__ prior,
        float* __restrict__ attn_out, float* __restrict__ lp_out) {
    __shared__ float Ks[16][448];
    __shared__ float Qs[16][16];
    __shared__ float k2sh[400];
    __shared__ float msh[400];
    __shared__ float q2sh[16];
    const int b = blockIdx.y;
    const int t10 = blockIdx.x * 16;
    const int tid = threadIdx.x;
    const int lane = tid & 63;
    const int w = tid >> 6;

    for (int s = tid; s < 400; s += 256) {
        k2sh[s] = k2s[b * T2_ + s];
        msh[s] = mask[b * T2_ + s] ? 1.f : 0.f;
    }
    if (tid < 16) q2sh[tid] = q2s[b * T1_ + t10 + tid];

    float acc[4][7] = {};
    for (int ci0 = 0; ci0 < 80; ci0 += 16) {
        __syncthreads();
        {
            int ci = tid >> 4, r = tid & 15;
            Qs[ci][r] = qf[((size_t)b * 80 + ci0 + ci) * T1_ + t10 + r];
        }
        #pragma unroll
        for (int ci = 0; ci < 16; ++ci) {
            const float* src = kf + ((size_t)b * 80 + ci0 + ci) * T2_;
            int s = tid;
            Ks[ci][s] = (s < 400) ? src[s] : 0.f;
            s = tid + 256;
            if (s < 448) Ks[ci][s] = (s < 400) ? src[s] : 0.f;
        }
        __syncthreads();
        #pragma unroll
        for (int ci = 0; ci < 16; ++ci) {
            float qv[4];
            #pragma unroll
            for (int i = 0; i < 4; ++i) qv[i] = Qs[ci][w * 4 + i];
            #pragma unroll
            for (int j = 0; j < 7; ++j) {
                float kv = Ks[ci][lane + 64 * j];
                #pragma unroll
                for (int i = 0; i < 4; ++i) acc[i][j] += qv[i] * kv;
            }
        }
    }

    const float NEG = -INFINITY;
    #pragma unroll
    for (int i = 0; i < 4; ++i) {
        const int r = w * 4 + i;
        const int t1 = t10 + r;
        const float q2v = q2sh[r];
        float l[7];
        #pragma unroll
        for (int j = 0; j < 7; ++j) {
            int s = lane + 64 * j;
            l[j] = (s < 400) ? (-TEMP * (q2v + k2sh[s] - 2.f * acc[i][j])) : NEG;
        }
        // log-softmax over the 400 cols (wave-wide reduce, width 64)
        float m = NEG;
        #pragma unroll
        for (int j = 0; j < 7; ++j) m = fmaxf(m, l[j]);
        #pragma unroll
        for (int off = 32; off >= 1; off >>= 1) m = fmaxf(m, __shfl_xor(m, off, 64));
        float sum = 0.f;
        #pragma unroll
        for (int j = 0; j < 7; ++j) sum += expf(l[j] - m);  // invalid lanes: exp(-inf)=0
        #pragma unroll
        for (int off = 32; off >= 1; off >>= 1) sum += __shfl_xor(sum, off, 64);
        const float lse = m + logf(sum);

        const float* prow = prior + ((size_t)b * T1_ + t1) * T2_;
        float* lpr = lp_out + ((size_t)b * T1_ + t1) * T2_;
        float* atr = attn_out + ((size_t)b * T1_ + t1) * T2_;
        float ml[7];
        #pragma unroll
        for (int j = 0; j < 7; ++j) {
            int s = lane + 64 * j;
            if (s < 400) {
                float lp = l[j] - lse + logf(prow[s] + 1e-8f);
                lpr[s] = lp;
                ml[j] = (msh[s] != 0.f) ? NEG : lp;
            } else {
                ml[j] = NEG;
            }
        }
        // masked softmax
        float m2 = NEG;
        #pragma unroll
        for (int j = 0; j < 7; ++j) m2 = fmaxf(m2, ml[j]);
        #pragma unroll
        for (int off = 32; off >= 1; off >>= 1) m2 = fmaxf(m2, __shfl_xor(m2, off, 64));
        float s2 = 0.f;
        #pragma unroll
        for (int j = 0; j < 7; ++j) s2 += expf(ml[j] - m2);
        #pragma unroll
        for (int off = 32; off >= 1; off >>= 1) s2 += __shfl_xor(s2, off, 64);
        const float inv = 1.f / s2;
        #pragma unroll
        for (int j = 0; j < 7; ++j) {
            int s = lane + 64 * j;
            if (s < 400) atr[s] = expf(ml[j] - m2) * inv;
        }
    }
}

extern "C" void kernel_launch(void* const* d_in, const int* in_sizes, int n_in,
                              void* d_out, int out_size, void* d_ws, size_t ws_size,
                              hipStream_t stream) {
    const float* queries = (const float*)d_in[0];
    const float* keys    = (const float*)d_in[1];
    const int*   mask    = (const int*)d_in[2];
    const float* prior   = (const float*)d_in[3];
    const float* se      = (const float*)d_in[4];
    const float* Wk1 = (const float*)d_in[5];
    const float* bk1 = (const float*)d_in[6];
    const float* Wk2 = (const float*)d_in[7];
    const float* bk2 = (const float*)d_in[8];
    const float* Wq1 = (const float*)d_in[9];
    const float* bq1 = (const float*)d_in[10];
    const float* Wq2 = (const float*)d_in[11];
    const float* bq2 = (const float*)d_in[12];
    const float* Wq3 = (const float*)d_in[13];
    const float* bq3 = (const float*)d_in[14];
    const float* Wks = (const float*)d_in[15];
    const float* bks = (const float*)d_in[16];
    const float* Wqs = (const float*)d_in[17];
    const float* bqs = (const float*)d_in[18];

    // workspace layout (floats); peak ~73 MB with bigA reuse (k1 then q1+q2a)
    float* ws   = (float*)d_ws;
    float* kb   = ws;                       // 32*512
    float* qb   = kb + 16384;               // 32*80
    float* q2s  = qb + 2560;                // 32*1600
    float* k2s  = q2s + 51200;              // 32*400
    float* kf   = k2s + 12800;              // 32*80*400   = 1,024,000
    float* bigA = kf + 1024000;             // 32*1024*400 = 13,107,200
    float* k1   = bigA;
    float* q1   = bigA;                     // reuse after k1 is consumed
    float* q2a  = bigA + 8192000;           // 32*80*1600
    float* qf   = bigA + 13107200;          // 32*80*1600

    float* attn_out = (float*)d_out;
    float* lp_out   = attn_out + (size_t)B_ * T1_ * T2_;

    bias_kernel<<<dim3(74), dim3(256), 0, stream>>>(se, Wks, bks, Wqs, bqs, kb, qb);
    // keys path
    conv_kernel<3, true,  true ><<<dim3(4, 32, 32), 256, 0, stream>>>(keys, Wk1, bk1, kb, k1, 1024, 512, 400);
    conv_kernel<1, false, false><<<dim3(4, 3, 32),  256, 0, stream>>>(k1, Wk2, bk2, nullptr, kf, 80, 1024, 400);
    sqsum_kernel<<<dim3(2, 32), 256, 0, stream>>>(kf, k2s, 80, 400);
    // query path
    conv_kernel<3, true,  true ><<<dim3(13, 5, 32), 256, 0, stream>>>(queries, Wq1, bq1, qb, q1, 160, 80, 1600);
    conv_kernel<1, true,  false><<<dim3(13, 3, 32), 256, 0, stream>>>(q1, Wq2, bq2, nullptr, q2a, 80, 160, 1600);
    conv_kernel<1, false, false><<<dim3(13, 3, 32), 256, 0, stream>>>(q2a, Wq3, bq3, nullptr, qf, 80, 80, 1600);
    sqsum_kernel<<<dim3(7, 32), 256, 0, stream>>>(qf, q2s, 80, 1600);
    // fused attention
    attn_kernel<<<dim3(100, 32), 256, 0, stream>>>(qf, kf, q2s, k2s, mask, prior, attn_out, lp_out);
}

// Round 3
// 1101.584 us; speedup vs baseline: 1.8644x; 1.8644x over previous
//
#include <hip/hip_runtime.h>
#include <math.h>

#define TEMP 0.0005f
#define B_    32
#define CMEL  80
#define CTXT  512
#define T1_   1600
#define T2_   400

typedef short short8 __attribute__((ext_vector_type(8)));
typedef float f32x4 __attribute__((ext_vector_type(4)));

__device__ inline unsigned short f2bf(float f) {
    unsigned u = __float_as_uint(f);
    u += 0x7FFF + ((u >> 16) & 1);
    return (unsigned short)(u >> 16);
}
__device__ inline float toF(float v) { return v; }
__device__ inline float toF(unsigned short v) { return __uint_as_float(((unsigned)v) << 16); }

// ---------------- speaker-embed bias vectors ----------------
__global__ void bias_kernel(const float* __restrict__ se,
                            const float* __restrict__ Wks, const float* __restrict__ bks,
                            const float* __restrict__ Wqs, const float* __restrict__ bqs,
                            float* __restrict__ kb, float* __restrict__ qb) {
    int tid = blockIdx.x * blockDim.x + threadIdx.x;
    const int nk = B_ * CTXT;
    if (tid < nk) {
        int b = tid / CTXT, c = tid % CTXT;
        const float4* s4 = reinterpret_cast<const float4*>(se + b * CTXT);
        const float4* w4 = reinterpret_cast<const float4*>(Wks + (size_t)c * CTXT);
        float acc = bks[c];
        #pragma unroll 4
        for (int j = 0; j < CTXT / 4; ++j) {
            float4 a = s4[j], w = w4[j];
            acc += a.x * w.x + a.y * w.y + a.z * w.z + a.w * w.w;
        }
        kb[tid] = acc;
    } else if (tid < nk + B_ * CMEL) {
        int t = tid - nk;
        int b = t / CMEL, c = t % CMEL;
        const float4* s4 = reinterpret_cast<const float4*>(se + b * CTXT);
        const float4* w4 = reinterpret_cast<const float4*>(Wqs + (size_t)c * CTXT);
        float acc = bqs[c];
        #pragma unroll 4
        for (int j = 0; j < CTXT / 4; ++j) {
            float4 a = s4[j], w = w4[j];
            acc += a.x * w.x + a.y * w.y + a.z * w.z + a.w * w.w;
        }
        qb[t] = acc;
    }
}

// ---------------- cast Wk1 -> Ab[co][dt*512+ci] bf16 ----------------
__global__ void castW_kernel(const float* __restrict__ W, unsigned short* __restrict__ Ab) {
    int o = blockIdx.x * 256 + threadIdx.x;
    if (o >= 1024 * 1536) return;
    int co = o / 1536;
    int rem = o - co * 1536;
    int dt = rem >> 9, ci = rem & 511;
    Ab[o] = f2bf(W[((size_t)co * 512 + ci) * 3 + dt]);
}

// ---------------- cast keys+bias -> Xt[b][t+1][ci] bf16 (transposed, padded) ----------------
// Xt rows: row r corresponds to t=r-1; rows with t outside [0,400) are zero. Rows 0..455.
__global__ void castX_kernel(const float* __restrict__ keys, const float* __restrict__ kb,
                             unsigned short* __restrict__ Xt) {
    __shared__ float tile[64][65];
    const int b = blockIdx.z;
    const int row0 = blockIdx.x * 64;
    const int ci0 = blockIdx.y * 64;
    const int tid = threadIdx.x;
    #pragma unroll
    for (int i = 0; i < 16; ++i) {
        int linear = i * 256 + tid;
        int ci_l = linear >> 6, t_l = linear & 63;
        int t = row0 + t_l - 1;
        float v = 0.f;
        if (t >= 0 && t < 400)
            v = keys[((size_t)b * 512 + ci0 + ci_l) * 400 + t] + kb[b * 512 + ci0 + ci_l];
        tile[t_l][ci_l] = v;
    }
    __syncthreads();
    #pragma unroll
    for (int i = 0; i < 16; ++i) {
        int linear = i * 256 + tid;
        int t_l = linear >> 6, ci_l = linear & 63;
        int row = row0 + t_l;
        if (row < 456)
            Xt[((size_t)b * 456 + row) * 512 + ci0 + ci_l] = f2bf(tile[t_l][ci_l]);
    }
}

// ---------------- keys conv1 via bf16 MFMA ----------------
// out[b,co,t] = relu(bk1[co] + sum_{dt,ci} W[co,ci,dt]*Xpad[ci][t+dt-1]), written bf16 [co][t]
__global__ __launch_bounds__(256) void conv1k_mfma(
        const unsigned short* __restrict__ Ab, const unsigned short* __restrict__ Xt,
        const float* __restrict__ bias, unsigned short* __restrict__ out) {
    __shared__ short As[3 * 128 * 40];
    __shared__ short Xs[66 * 40];
    const int b = blockIdx.z;
    const int co0 = blockIdx.y * 128;
    const int t0 = blockIdx.x * 64;
    const int tid = threadIdx.x;
    const int lane = tid & 63, w = tid >> 6;
    const int wm = w >> 1, wn = w & 1;
    const int l15 = lane & 15, quad = lane >> 4;
    f32x4 acc[4][2];
    #pragma unroll
    for (int mt = 0; mt < 4; ++mt)
        #pragma unroll
        for (int nt = 0; nt < 2; ++nt)
            acc[mt][nt] = (f32x4){0.f, 0.f, 0.f, 0.f};

    for (int ci0 = 0; ci0 < 512; ci0 += 32) {
        __syncthreads();
        // stage A: 3 chunks of [128 co][32 ci], 1536 x 16B
        #pragma unroll
        for (int i = 0; i < 6; ++i) {
            int linear = i * 256 + tid;
            int dt = linear >> 9;
            int rem = linear & 511;
            int r = rem >> 2, c16 = rem & 3;
            int4 v = *(const int4*)(Ab + (size_t)(co0 + r) * 1536 + dt * 512 + ci0 + c16 * 8);
            *(int4*)(As + (dt * 128 + r) * 40 + c16 * 8) = v;
        }
        // stage X: [66 rows][32 ci], 264 x 16B
        #pragma unroll
        for (int i = 0; i < 2; ++i) {
            int c = i * 256 + tid;
            if (c < 264) {
                int row = c >> 2, c16 = c & 3;
                int4 v = *(const int4*)(Xt + ((size_t)b * 456 + t0 + row) * 512 + ci0 + c16 * 8);
                *(int4*)(Xs + row * 40 + c16 * 8) = v;
            }
        }
        __syncthreads();
        #pragma unroll
        for (int dt = 0; dt < 3; ++dt) {
            short8 af[4], bfr[2];
            #pragma unroll
            for (int mt = 0; mt < 4; ++mt)
                af[mt] = *(const short8*)(As + (dt * 128 + wm * 64 + mt * 16 + l15) * 40 + quad * 8);
            #pragma unroll
            for (int nt = 0; nt < 2; ++nt)
                bfr[nt] = *(const short8*)(Xs + (wn * 32 + nt * 16 + l15 + dt) * 40 + quad * 8);
            #pragma unroll
            for (int mt = 0; mt < 4; ++mt)
                #pragma unroll
                for (int nt = 0; nt < 2; ++nt)
                    acc[mt][nt] = __builtin_amdgcn_mfma_f32_16x16x32_bf16(af[mt], bfr[nt], acc[mt][nt], 0, 0, 0);
        }
    }
    // epilogue: C row = quad*4+reg (co), col = l15 (t)
    #pragma unroll
    for (int mt = 0; mt < 4; ++mt) {
        int cob = co0 + wm * 64 + mt * 16 + quad * 4;
        float bv[4];
        #pragma unroll
        for (int r = 0; r < 4; ++r) bv[r] = bias[cob + r];
        #pragma unroll
        for (int nt = 0; nt < 2; ++nt) {
            int t = t0 + wn * 32 + nt * 16 + l15;
            if (t >= 400) continue;
            #pragma unroll
            for (int r = 0; r < 4; ++r) {
                float v = acc[mt][nt][r] + bv[r];
                v = fmaxf(v, 0.f);
                out[((size_t)b * 1024 + cob + r) * 400 + t] = f2bf(v);
            }
        }
    }
}

// ---------------- generic conv1d (fp32 compute, templated input type) ----------------
template<int KS, bool RELU, bool INBIAS, typename TIN>
__global__ __launch_bounds__(256) void conv_kernel(
        const TIN* __restrict__ in, const float* __restrict__ W,
        const float* __restrict__ bias, const float* __restrict__ inBias,
        float* __restrict__ out, int Cout, int Cin, int T) {
    constexpr int PAD = (KS - 1) / 2;
    constexpr int WIDTH = 128 + KS - 1;
    __shared__ float Xs[8][WIDTH];
    __shared__ float Ws[32][8 * KS];
    const int b = blockIdx.z;
    const int co0 = blockIdx.y * 32;
    const int t0 = blockIdx.x * 128;
    const int tid = threadIdx.x;
    const int tt = tid & 31;
    const int tc = tid >> 5;
    float acc[4][4] = {};

    for (int ci0 = 0; ci0 < Cin; ci0 += 8) {
        {
            const int row = tc;
            const TIN* src = in + ((size_t)b * Cin + ci0 + row) * T;
            float ib = 0.f;
            if (INBIAS) ib = inBias[b * Cin + ci0 + row];
            for (int l = tt; l < WIDTH; l += 32) {
                int t = t0 - PAD + l;
                float v = 0.f;
                if (t >= 0 && t < T) v = toF(src[t]) + ib;
                Xs[row][l] = v;
            }
        }
        for (int idx = tid; idx < 32 * 8 * KS; idx += 256) {
            int row = idx / (8 * KS);
            int col = idx - row * (8 * KS);
            int co = co0 + row;
            float v = 0.f;
            if (co < Cout) v = W[((size_t)co * Cin + ci0) * KS + col];
            Ws[row][col] = v;
        }
        __syncthreads();
        #pragma unroll
        for (int ci = 0; ci < 8; ++ci) {
            #pragma unroll
            for (int dt = 0; dt < KS; ++dt) {
                float xv[4], wv[4];
                #pragma unroll
                for (int j = 0; j < 4; ++j) xv[j] = Xs[ci][tt + 32 * j + dt];
                #pragma unroll
                for (int i = 0; i < 4; ++i) wv[i] = Ws[tc + 8 * i][ci * KS + dt];
                #pragma unroll
                for (int i = 0; i < 4; ++i)
                    #pragma unroll
                    for (int j = 0; j < 4; ++j)
                        acc[i][j] += wv[i] * xv[j];
            }
        }
        __syncthreads();
    }
    #pragma unroll
    for (int i = 0; i < 4; ++i) {
        int co = co0 + tc + 8 * i;
        if (co >= Cout) continue;
        float bv = bias[co];
        #pragma unroll
        for (int j = 0; j < 4; ++j) {
            int t = t0 + tt + 32 * j;
            if (t >= T) continue;
            float v = acc[i][j] + bv;
            if (RELU) v = fmaxf(v, 0.f);
            out[((size_t)b * Cout + co) * T + t] = v;
        }
    }
}

// ---------------- channel sum-of-squares ----------------
__global__ void sqsum_kernel(const float* __restrict__ x, float* __restrict__ out,
                             int C, int T) {
    int b = blockIdx.y;
    int t = blockIdx.x * 256 + threadIdx.x;
    if (t >= T) return;
    const float* p = x + (size_t)b * C * T + t;
    float acc = 0.f;
    #pragma unroll 4
    for (int c = 0; c < 80; ++c) { float v = p[(size_t)c * T]; acc += v * v; }
    out[b * T + t] = acc;
}

// ---------------- fused qk GEMM + log_softmax + prior + masked softmax ----------------
__global__ __launch_bounds__(256) void attn_kernel(
        const float* __restrict__ qf, const float* __restrict__ kf,
        const float* __restrict__ q2s, const float* __restrict__ k2s,
        const int* __restrict__ mask, const float* __restrict__ prior,
        float* __restrict__ attn_out, float* __restrict__ lp_out) {
    __shared__ float Ks[16][448];
    __shared__ float Qs[16][16];
    __shared__ float k2sh[400];
    __shared__ float msh[400];
    __shared__ float q2sh[16];
    const int b = blockIdx.y;
    const int t10 = blockIdx.x * 16;
    const int tid = threadIdx.x;
    const int lane = tid & 63;
    const int w = tid >> 6;

    for (int s = tid; s < 400; s += 256) {
        k2sh[s] = k2s[b * T2_ + s];
        msh[s] = mask[b * T2_ + s] ? 1.f : 0.f;
    }
    if (tid < 16) q2sh[tid] = q2s[b * T1_ + t10 + tid];

    float acc[4][7] = {};
    for (int ci0 = 0; ci0 < 80; ci0 += 16) {
        __syncthreads();
        {
            int ci = tid >> 4, r = tid & 15;
            Qs[ci][r] = qf[((size_t)b * 80 + ci0 + ci) * T1_ + t10 + r];
        }
        #pragma unroll
        for (int ci = 0; ci < 16; ++ci) {
            const float* src = kf + ((size_t)b * 80 + ci0 + ci) * T2_;
            int s = tid;
            Ks[ci][s] = (s < 400) ? src[s] : 0.f;
            s = tid + 256;
            if (s < 448) Ks[ci][s] = (s < 400) ? src[s] : 0.f;
        }
        __syncthreads();
        #pragma unroll
        for (int ci = 0; ci < 16; ++ci) {
            float qv[4];
            #pragma unroll
            for (int i = 0; i < 4; ++i) qv[i] = Qs[ci][w * 4 + i];
            #pragma unroll
            for (int j = 0; j < 7; ++j) {
                float kv = Ks[ci][lane + 64 * j];
                #pragma unroll
                for (int i = 0; i < 4; ++i) acc[i][j] += qv[i] * kv;
            }
        }
    }

    const float NEG = -INFINITY;
    #pragma unroll
    for (int i = 0; i < 4; ++i) {
        const int r = w * 4 + i;
        const int t1 = t10 + r;
        const float q2v = q2sh[r];
        float l[7];
        #pragma unroll
        for (int j = 0; j < 7; ++j) {
            int s = lane + 64 * j;
            l[j] = (s < 400) ? (-TEMP * (q2v + k2sh[s] - 2.f * acc[i][j])) : NEG;
        }
        float m = NEG;
        #pragma unroll
        for (int j = 0; j < 7; ++j) m = fmaxf(m, l[j]);
        #pragma unroll
        for (int off = 32; off >= 1; off >>= 1) m = fmaxf(m, __shfl_xor(m, off, 64));
        float sum = 0.f;
        #pragma unroll
        for (int j = 0; j < 7; ++j) sum += expf(l[j] - m);
        #pragma unroll
        for (int off = 32; off >= 1; off >>= 1) sum += __shfl_xor(sum, off, 64);
        const float lse = m + logf(sum);

        const float* prow = prior + ((size_t)b * T1_ + t1) * T2_;
        float* lpr = lp_out + ((size_t)b * T1_ + t1) * T2_;
        float* atr = attn_out + ((size_t)b * T1_ + t1) * T2_;
        float ml[7];
        #pragma unroll
        for (int j = 0; j < 7; ++j) {
            int s = lane + 64 * j;
            if (s < 400) {
                float lp = l[j] - lse + logf(prow[s] + 1e-8f);
                lpr[s] = lp;
                ml[j] = (msh[s] != 0.f) ? NEG : lp;
            } else {
                ml[j] = NEG;
            }
        }
        float m2 = NEG;
        #pragma unroll
        for (int j = 0; j < 7; ++j) m2 = fmaxf(m2, ml[j]);
        #pragma unroll
        for (int off = 32; off >= 1; off >>= 1) m2 = fmaxf(m2, __shfl_xor(m2, off, 64));
        float s2 = 0.f;
        #pragma unroll
        for (int j = 0; j < 7; ++j) s2 += expf(ml[j] - m2);
        #pragma unroll
        for (int off = 32; off >= 1; off >>= 1) s2 += __shfl_xor(s2, off, 64);
        const float inv = 1.f / s2;
        #pragma unroll
        for (int j = 0; j < 7; ++j) {
            int s = lane + 64 * j;
            if (s < 400) atr[s] = expf(ml[j] - m2) * inv;
        }
    }
}

extern "C" void kernel_launch(void* const* d_in, const int* in_sizes, int n_in,
                              void* d_out, int out_size, void* d_ws, size_t ws_size,
                              hipStream_t stream) {
    const float* queries = (const float*)d_in[0];
    const float* keys    = (const float*)d_in[1];
    const int*   mask    = (const int*)d_in[2];
    const float* prior   = (const float*)d_in[3];
    const float* se      = (const float*)d_in[4];
    const float* Wk1 = (const float*)d_in[5];
    const float* bk1 = (const float*)d_in[6];
    const float* Wk2 = (const float*)d_in[7];
    const float* bk2 = (const float*)d_in[8];
    const float* Wq1 = (const float*)d_in[9];
    const float* bq1 = (const float*)d_in[10];
    const float* Wq2 = (const float*)d_in[11];
    const float* bq2 = (const float*)d_in[12];
    const float* Wq3 = (const float*)d_in[13];
    const float* bq3 = (const float*)d_in[14];
    const float* Wks = (const float*)d_in[15];
    const float* bks = (const float*)d_in[16];
    const float* Wqs = (const float*)d_in[17];
    const float* bqs = (const float*)d_in[18];

    // workspace layout (float units).
    // fixed head: kb(16384) qb(2560) q2s(51200) k2s(12800) kf(1024000) -> base = 1,106,944
    // keys phase from base: k1b 32*1024*400 bf16 = 6,553,600 fl | Ab 1024*1536 bf16 = 786,432 fl
    //                       | Xt 32*456*512 bf16 = 3,735,552 fl  (peak 48.7 MB)
    // q phase from base (keys-phase dead): q1 8,192,000 fl | q2a 4,096,000 fl (peak 53.6 MB)
    float* ws   = (float*)d_ws;
    float* kb   = ws;
    float* qb   = ws + 16384;
    float* q2s  = ws + 18944;
    float* k2s  = ws + 70144;
    float* kf   = ws + 82944;
    const size_t base = 1106944;
    unsigned short* k1b = (unsigned short*)(ws + base);
    unsigned short* Ab  = (unsigned short*)(ws + base + 6553600);
    unsigned short* Xt  = (unsigned short*)(ws + base + 6553600 + 786432);
    float* q1  = ws + base;
    float* q2a = ws + base + 8192000;
    float* qfv = ws + base;  // overlays dead q1 after q2a conv

    float* attn_out = (float*)d_out;
    float* lp_out   = attn_out + (size_t)B_ * T1_ * T2_;

    bias_kernel<<<dim3(74), dim3(256), 0, stream>>>(se, Wks, bks, Wqs, bqs, kb, qb);
    // keys path (bf16 MFMA conv1)
    castW_kernel<<<dim3(6144), dim3(256), 0, stream>>>(Wk1, Ab);
    castX_kernel<<<dim3(8, 8, 32), dim3(256), 0, stream>>>(keys, kb, Xt);
    conv1k_mfma<<<dim3(7, 8, 32), dim3(256), 0, stream>>>(Ab, Xt, bk1, k1b);
    conv_kernel<1, false, false, unsigned short><<<dim3(4, 3, 32), 256, 0, stream>>>(k1b, Wk2, bk2, nullptr, kf, 80, 1024, 400);
    sqsum_kernel<<<dim3(2, 32), 256, 0, stream>>>(kf, k2s, 80, 400);
    // query path (fp32)
    conv_kernel<3, true,  true,  float><<<dim3(13, 5, 32), 256, 0, stream>>>(queries, Wq1, bq1, qb, q1, 160, 80, 1600);
    conv_kernel<1, true,  false, float><<<dim3(13, 3, 32), 256, 0, stream>>>(q1, Wq2, bq2, nullptr, q2a, 80, 160, 1600);
    conv_kernel<1, false, false, float><<<dim3(13, 3, 32), 256, 0, stream>>>(q2a, Wq3, bq3, nullptr, qfv, 80, 80, 1600);
    sqsum_kernel<<<dim3(7, 32), 256, 0, stream>>>(qfv, q2s, 80, 1600);
    // fused attention
    attn_kernel<<<dim3(100, 32), 256, 0, stream>>>(qfv, kf, q2s, k2s, mask, prior, attn_out, lp_out);
}

// Round 4
// 981.109 us; speedup vs baseline: 2.0933x; 1.1228x over previous
//
#include <hip/hip_runtime.h>
#include <math.h>

#define TEMP 0.0005f
#define B_    32
#define CMEL  80
#define CTXT  512
#define T1_   1600
#define T2_   400

typedef short short8 __attribute__((ext_vector_type(8)));
typedef float f32x4 __attribute__((ext_vector_type(4)));

__device__ inline unsigned short f2bf(float f) {
    unsigned u = __float_as_uint(f);
    u += 0x7FFF + ((u >> 16) & 1);
    return (unsigned short)(u >> 16);
}
__device__ inline float toF(float v) { return v; }
__device__ inline float toF(unsigned short v) { return __uint_as_float(((unsigned)v) << 16); }

// ---------------- speaker-embed bias vectors ----------------
__global__ void bias_kernel(const float* __restrict__ se,
                            const float* __restrict__ Wks, const float* __restrict__ bks,
                            const float* __restrict__ Wqs, const float* __restrict__ bqs,
                            float* __restrict__ kb, float* __restrict__ qb) {
    int tid = blockIdx.x * blockDim.x + threadIdx.x;
    const int nk = B_ * CTXT;
    if (tid < nk) {
        int b = tid / CTXT, c = tid % CTXT;
        const float4* s4 = reinterpret_cast<const float4*>(se + b * CTXT);
        const float4* w4 = reinterpret_cast<const float4*>(Wks + (size_t)c * CTXT);
        float acc = bks[c];
        #pragma unroll 4
        for (int j = 0; j < CTXT / 4; ++j) {
            float4 a = s4[j], w = w4[j];
            acc += a.x * w.x + a.y * w.y + a.z * w.z + a.w * w.w;
        }
        kb[tid] = acc;
    } else if (tid < nk + B_ * CMEL) {
        int t = tid - nk;
        int b = t / CMEL, c = t % CMEL;
        const float4* s4 = reinterpret_cast<const float4*>(se + b * CTXT);
        const float4* w4 = reinterpret_cast<const float4*>(Wqs + (size_t)c * CTXT);
        float acc = bqs[c];
        #pragma unroll 4
        for (int j = 0; j < CTXT / 4; ++j) {
            float4 a = s4[j], w = w4[j];
            acc += a.x * w.x + a.y * w.y + a.z * w.z + a.w * w.w;
        }
        qb[t] = acc;
    }
}

// ---------------- cast Wk1 -> Ab[co][dt*512+ci] bf16 ----------------
__global__ void castW_kernel(const float* __restrict__ W, unsigned short* __restrict__ Ab) {
    int o = blockIdx.x * 256 + threadIdx.x;
    if (o >= 1024 * 1536) return;
    int co = o / 1536;
    int rem = o - co * 1536;
    int dt = rem >> 9, ci = rem & 511;
    Ab[o] = f2bf(W[((size_t)co * 512 + ci) * 3 + dt]);
}

// ---------------- cast keys+bias -> Xt[b][t+1][ci] bf16 (transposed, padded) ----------------
__global__ void castX_kernel(const float* __restrict__ keys, const float* __restrict__ kb,
                             unsigned short* __restrict__ Xt) {
    __shared__ float tile[64][65];
    const int b = blockIdx.z;
    const int row0 = blockIdx.x * 64;
    const int ci0 = blockIdx.y * 64;
    const int tid = threadIdx.x;
    #pragma unroll
    for (int i = 0; i < 16; ++i) {
        int linear = i * 256 + tid;
        int ci_l = linear >> 6, t_l = linear & 63;
        int t = row0 + t_l - 1;
        float v = 0.f;
        if (t >= 0 && t < 400)
            v = keys[((size_t)b * 512 + ci0 + ci_l) * 400 + t] + kb[b * 512 + ci0 + ci_l];
        tile[t_l][ci_l] = v;
    }
    __syncthreads();
    #pragma unroll
    for (int i = 0; i < 16; ++i) {
        int linear = i * 256 + tid;
        int t_l = linear >> 6, ci_l = linear & 63;
        int row = row0 + t_l;
        if (row < 456)
            Xt[((size_t)b * 456 + row) * 512 + ci0 + ci_l] = f2bf(tile[t_l][ci_l]);
    }
}

// ---------------- keys conv1 via bf16 MFMA ----------------
__global__ __launch_bounds__(256) void conv1k_mfma(
        const unsigned short* __restrict__ Ab, const unsigned short* __restrict__ Xt,
        const float* __restrict__ bias, unsigned short* __restrict__ out) {
    __shared__ short As[3 * 128 * 40];
    __shared__ short Xs[66 * 40];
    const int b = blockIdx.z;
    const int co0 = blockIdx.y * 128;
    const int t0 = blockIdx.x * 64;
    const int tid = threadIdx.x;
    const int lane = tid & 63, w = tid >> 6;
    const int wm = w >> 1, wn = w & 1;
    const int l15 = lane & 15, quad = lane >> 4;
    f32x4 acc[4][2];
    #pragma unroll
    for (int mt = 0; mt < 4; ++mt)
        #pragma unroll
        for (int nt = 0; nt < 2; ++nt)
            acc[mt][nt] = (f32x4){0.f, 0.f, 0.f, 0.f};

    for (int ci0 = 0; ci0 < 512; ci0 += 32) {
        __syncthreads();
        #pragma unroll
        for (int i = 0; i < 6; ++i) {
            int linear = i * 256 + tid;
            int dt = linear >> 9;
            int rem = linear & 511;
            int r = rem >> 2, c16 = rem & 3;
            int4 v = *(const int4*)(Ab + (size_t)(co0 + r) * 1536 + dt * 512 + ci0 + c16 * 8);
            *(int4*)(As + (dt * 128 + r) * 40 + c16 * 8) = v;
        }
        #pragma unroll
        for (int i = 0; i < 2; ++i) {
            int c = i * 256 + tid;
            if (c < 264) {
                int row = c >> 2, c16 = c & 3;
                int4 v = *(const int4*)(Xt + ((size_t)b * 456 + t0 + row) * 512 + ci0 + c16 * 8);
                *(int4*)(Xs + row * 40 + c16 * 8) = v;
            }
        }
        __syncthreads();
        #pragma unroll
        for (int dt = 0; dt < 3; ++dt) {
            short8 af[4], bfr[2];
            #pragma unroll
            for (int mt = 0; mt < 4; ++mt)
                af[mt] = *(const short8*)(As + (dt * 128 + wm * 64 + mt * 16 + l15) * 40 + quad * 8);
            #pragma unroll
            for (int nt = 0; nt < 2; ++nt)
                bfr[nt] = *(const short8*)(Xs + (wn * 32 + nt * 16 + l15 + dt) * 40 + quad * 8);
            #pragma unroll
            for (int mt = 0; mt < 4; ++mt)
                #pragma unroll
                for (int nt = 0; nt < 2; ++nt)
                    acc[mt][nt] = __builtin_amdgcn_mfma_f32_16x16x32_bf16(af[mt], bfr[nt], acc[mt][nt], 0, 0, 0);
        }
    }
    #pragma unroll
    for (int mt = 0; mt < 4; ++mt) {
        int cob = co0 + wm * 64 + mt * 16 + quad * 4;
        float bv[4];
        #pragma unroll
        for (int r = 0; r < 4; ++r) bv[r] = bias[cob + r];
        #pragma unroll
        for (int nt = 0; nt < 2; ++nt) {
            int t = t0 + wn * 32 + nt * 16 + l15;
            if (t >= 400) continue;
            #pragma unroll
            for (int r = 0; r < 4; ++r) {
                float v = acc[mt][nt][r] + bv[r];
                v = fmaxf(v, 0.f);
                out[((size_t)b * 1024 + cob + r) * 400 + t] = f2bf(v);
            }
        }
    }
}

// ---------------- generic conv1d (fp32 compute, templated input type) ----------------
template<int KS, bool RELU, bool INBIAS, typename TIN>
__global__ __launch_bounds__(256) void conv_kernel(
        const TIN* __restrict__ in, const float* __restrict__ W,
        const float* __restrict__ bias, const float* __restrict__ inBias,
        float* __restrict__ out, int Cout, int Cin, int T) {
    constexpr int PAD = (KS - 1) / 2;
    constexpr int WIDTH = 128 + KS - 1;
    __shared__ float Xs[8][WIDTH];
    __shared__ float Ws[32][8 * KS];
    const int b = blockIdx.z;
    const int co0 = blockIdx.y * 32;
    const int t0 = blockIdx.x * 128;
    const int tid = threadIdx.x;
    const int tt = tid & 31;
    const int tc = tid >> 5;
    float acc[4][4] = {};

    for (int ci0 = 0; ci0 < Cin; ci0 += 8) {
        {
            const int row = tc;
            const TIN* src = in + ((size_t)b * Cin + ci0 + row) * T;
            float ib = 0.f;
            if (INBIAS) ib = inBias[b * Cin + ci0 + row];
            for (int l = tt; l < WIDTH; l += 32) {
                int t = t0 - PAD + l;
                float v = 0.f;
                if (t >= 0 && t < T) v = toF(src[t]) + ib;
                Xs[row][l] = v;
            }
        }
        for (int idx = tid; idx < 32 * 8 * KS; idx += 256) {
            int row = idx / (8 * KS);
            int col = idx - row * (8 * KS);
            int co = co0 + row;
            float v = 0.f;
            if (co < Cout) v = W[((size_t)co * Cin + ci0) * KS + col];
            Ws[row][col] = v;
        }
        __syncthreads();
        #pragma unroll
        for (int ci = 0; ci < 8; ++ci) {
            #pragma unroll
            for (int dt = 0; dt < KS; ++dt) {
                float xv[4], wv[4];
                #pragma unroll
                for (int j = 0; j < 4; ++j) xv[j] = Xs[ci][tt + 32 * j + dt];
                #pragma unroll
                for (int i = 0; i < 4; ++i) wv[i] = Ws[tc + 8 * i][ci * KS + dt];
                #pragma unroll
                for (int i = 0; i < 4; ++i)
                    #pragma unroll
                    for (int j = 0; j < 4; ++j)
                        acc[i][j] += wv[i] * xv[j];
            }
        }
        __syncthreads();
    }
    #pragma unroll
    for (int i = 0; i < 4; ++i) {
        int co = co0 + tc + 8 * i;
        if (co >= Cout) continue;
        float bv = bias[co];
        #pragma unroll
        for (int j = 0; j < 4; ++j) {
            int t = t0 + tt + 32 * j;
            if (t >= T) continue;
            float v = acc[i][j] + bv;
            if (RELU) v = fmaxf(v, 0.f);
            out[((size_t)b * Cout + co) * T + t] = v;
        }
    }
}

// ---------------- channel sum-of-squares ----------------
__global__ void sqsum_kernel(const float* __restrict__ x, float* __restrict__ out,
                             int C, int T) {
    int b = blockIdx.y;
    int t = blockIdx.x * 256 + threadIdx.x;
    if (t >= T) return;
    const float* p = x + (size_t)b * C * T + t;
    float acc = 0.f;
    #pragma unroll 4
    for (int c = 0; c < 80; ++c) { float v = p[(size_t)c * T]; acc += v * v; }
    out[b * T + t] = acc;
}

// ---------------- transpose-cast [b][80][T] fp32 -> [b][t][96] bf16 with dist channels ----
// c<80: value; ISQ: c80=1, c81=-0.5*sq[t]; !ISQ: c80=-0.5*sq[t], c81=1; c>=82: 0.
template<bool ISQ>
__global__ __launch_bounds__(256) void transpose_cast_kernel(
        const float* __restrict__ in, const float* __restrict__ sq,
        unsigned short* __restrict__ out, int T) {
    __shared__ float tile[80][65];
    const int b = blockIdx.y;
    const int t0 = blockIdx.x * 64;
    const int tid = threadIdx.x;
    {
        int tl = tid & 63, c0 = tid >> 6;
        if (t0 + tl < T)
            for (int c = c0; c < 80; c += 4)
                tile[c][tl] = in[((size_t)b * 80 + c) * T + t0 + tl];
    }
    __syncthreads();
    int row = tid >> 2, cg = tid & 3;
    int t = t0 + row;
    if (t >= T) return;
    float e80, e81;
    if (ISQ) { e80 = 1.0f; e81 = -0.5f * sq[b * T + t]; }
    else     { e80 = -0.5f * sq[b * T + t]; e81 = 1.0f; }
    unsigned int* orow = (unsigned int*)(out + ((size_t)b * T + t) * 96 + cg * 24);
    #pragma unroll
    for (int jj = 0; jj < 12; ++jj) {
        int c0 = cg * 24 + jj * 2, c1 = c0 + 1;
        float f0 = (c0 < 80) ? tile[c0][row] : (c0 == 80 ? e80 : (c0 == 81 ? e81 : 0.f));
        float f1 = (c1 < 80) ? tile[c1][row] : (c1 == 80 ? e80 : (c1 == 81 ? e81 : 0.f));
        orow[jj] = (unsigned)f2bf(f0) | ((unsigned)f2bf(f1) << 16);
    }
}

// ---------------- fused qk MFMA + log_softmax + prior + masked softmax ----------------
// logit = 2*TEMP * (qT[t1,:96] . kT[s,:96])  (distance folded into channels 80/81)
__global__ __launch_bounds__(256) void attn_mfma_kernel(
        const unsigned short* __restrict__ qT, const unsigned short* __restrict__ kT,
        const int* __restrict__ mask, const float* __restrict__ prior,
        float* __restrict__ attn_out, float* __restrict__ lp_out) {
    __shared__ float msh[400];
    const int b = blockIdx.y;
    const int t10 = blockIdx.x * 64;
    const int tid = threadIdx.x;
    const int lane = tid & 63, w = tid >> 6;
    const int l15 = lane & 15, quad = lane >> 4;
    for (int s = tid; s < 400; s += 256)
        msh[s] = mask[b * T2_ + s] ? 1.f : 0.f;
    __syncthreads();

    // A fragments: rows t10 + w*16 + l15, K-contiguous
    const unsigned short* qrow = qT + ((size_t)b * T1_ + t10 + w * 16 + l15) * 96;
    short8 af[3];
    #pragma unroll
    for (int kc = 0; kc < 3; ++kc)
        af[kc] = *(const short8*)(qrow + kc * 32 + quad * 8);

    f32x4 acc[25];
    #pragma unroll
    for (int ns = 0; ns < 25; ++ns) acc[ns] = (f32x4){0.f, 0.f, 0.f, 0.f};
    const unsigned short* kbase = kT + (size_t)b * T2_ * 96 + l15 * 96 + quad * 8;
    #pragma unroll
    for (int ns = 0; ns < 25; ++ns) {
        #pragma unroll
        for (int kc = 0; kc < 3; ++kc) {
            short8 bf = *(const short8*)(kbase + ns * 16 * 96 + kc * 32);
            acc[ns] = __builtin_amdgcn_mfma_f32_16x16x32_bf16(af[kc], bf, acc[ns], 0, 0, 0);
        }
    }

    const float NEG = -INFINITY;
    const float K2T = 2.0f * TEMP;
    #pragma unroll
    for (int r = 0; r < 4; ++r) {
        const int t1 = t10 + w * 16 + quad * 4 + r;
        float l[25];
        #pragma unroll
        for (int ns = 0; ns < 25; ++ns) l[ns] = K2T * acc[ns][r];
        float m = l[0];
        #pragma unroll
        for (int ns = 1; ns < 25; ++ns) m = fmaxf(m, l[ns]);
        #pragma unroll
        for (int off = 1; off <= 8; off <<= 1) m = fmaxf(m, __shfl_xor(m, off, 16));
        float sum = 0.f;
        #pragma unroll
        for (int ns = 0; ns < 25; ++ns) sum += __expf(l[ns] - m);
        #pragma unroll
        for (int off = 1; off <= 8; off <<= 1) sum += __shfl_xor(sum, off, 16);
        const float lse = m + __logf(sum);

        const float* prow = prior + ((size_t)b * T1_ + t1) * T2_;
        float* lpr = lp_out + ((size_t)b * T1_ + t1) * T2_;
        float* atr = attn_out + ((size_t)b * T1_ + t1) * T2_;
        // write logprob; l[] becomes lp
        #pragma unroll
        for (int ns = 0; ns < 25; ++ns) {
            int s = ns * 16 + l15;
            float lp = l[ns] - lse + __logf(prow[s] + 1e-8f);
            lpr[s] = lp;
            l[ns] = (msh[s] != 0.f) ? NEG : lp;
        }
        float m2 = NEG;
        #pragma unroll
        for (int ns = 0; ns < 25; ++ns) m2 = fmaxf(m2, l[ns]);
        #pragma unroll
        for (int off = 1; off <= 8; off <<= 1) m2 = fmaxf(m2, __shfl_xor(m2, off, 16));
        float s2 = 0.f;
        #pragma unroll
        for (int ns = 0; ns < 25; ++ns) { float e = __expf(l[ns] - m2); s2 += e; l[ns] = e; }
        #pragma unroll
        for (int off = 1; off <= 8; off <<= 1) s2 += __shfl_xor(s2, off, 16);
        const float inv = 1.f / s2;
        #pragma unroll
        for (int ns = 0; ns < 25; ++ns) atr[ns * 16 + l15] = l[ns] * inv;
    }
}

extern "C" void kernel_launch(void* const* d_in, const int* in_sizes, int n_in,
                              void* d_out, int out_size, void* d_ws, size_t ws_size,
                              hipStream_t stream) {
    const float* queries = (const float*)d_in[0];
    const float* keys    = (const float*)d_in[1];
    const int*   mask    = (const int*)d_in[2];
    const float* prior   = (const float*)d_in[3];
    const float* se      = (const float*)d_in[4];
    const float* Wk1 = (const float*)d_in[5];
    const float* bk1 = (const float*)d_in[6];
    const float* Wk2 = (const float*)d_in[7];
    const float* bk2 = (const float*)d_in[8];
    const float* Wq1 = (const float*)d_in[9];
    const float* bq1 = (const float*)d_in[10];
    const float* Wq2 = (const float*)d_in[11];
    const float* bq2 = (const float*)d_in[12];
    const float* Wq3 = (const float*)d_in[13];
    const float* bq3 = (const float*)d_in[14];
    const float* Wks = (const float*)d_in[15];
    const float* bks = (const float*)d_in[16];
    const float* Wqs = (const float*)d_in[17];
    const float* bqs = (const float*)d_in[18];

    // workspace layout (float units):
    // head: kb 0(16384) | qb 16384(2560) | q2s 18944(51200) | k2s 70144(12800)
    //       | kf 82944(1,024,000) | qT 1,106,944(2,457,600) | kT 3,564,544(614,400)
    // base2 = 4,178,944.
    // keys phase: k1b(6,553,600) | Ab(786,432) | Xt(3,735,552)  -> peak 61.0 MB
    // q phase:    q1(8,192,000) | q2a(4,096,000)                -> peak 65.9 MB (<73 MB proven)
    float* ws   = (float*)d_ws;
    float* kb   = ws;
    float* qb   = ws + 16384;
    float* q2s  = ws + 18944;
    float* k2s  = ws + 70144;
    float* kf   = ws + 82944;
    unsigned short* qT = (unsigned short*)(ws + 1106944);
    unsigned short* kT = (unsigned short*)(ws + 3564544);
    const size_t base2 = 4178944;
    unsigned short* k1b = (unsigned short*)(ws + base2);
    unsigned short* Ab  = (unsigned short*)(ws + base2 + 6553600);
    unsigned short* Xt  = (unsigned short*)(ws + base2 + 7340032);
    float* q1  = ws + base2;
    float* q2a = ws + base2 + 8192000;
    float* qfv = ws + base2;  // overlays dead q1

    float* attn_out = (float*)d_out;
    float* lp_out   = attn_out + (size_t)B_ * T1_ * T2_;

    bias_kernel<<<dim3(74), dim3(256), 0, stream>>>(se, Wks, bks, Wqs, bqs, kb, qb);
    // keys path (bf16 MFMA conv1)
    castW_kernel<<<dim3(6144), dim3(256), 0, stream>>>(Wk1, Ab);
    castX_kernel<<<dim3(8, 8, 32), dim3(256), 0, stream>>>(keys, kb, Xt);
    conv1k_mfma<<<dim3(7, 8, 32), dim3(256), 0, stream>>>(Ab, Xt, bk1, k1b);
    conv_kernel<1, false, false, unsigned short><<<dim3(4, 3, 32), 256, 0, stream>>>(k1b, Wk2, bk2, nullptr, kf, 80, 1024, 400);
    sqsum_kernel<<<dim3(2, 32), 256, 0, stream>>>(kf, k2s, 80, 400);
    transpose_cast_kernel<false><<<dim3(7, 32), 256, 0, stream>>>(kf, k2s, kT, 400);
    // query path (fp32)
    conv_kernel<3, true,  true,  float><<<dim3(13, 5, 32), 256, 0, stream>>>(queries, Wq1, bq1, qb, q1, 160, 80, 1600);
    conv_kernel<1, true,  false, float><<<dim3(13, 3, 32), 256, 0, stream>>>(q1, Wq2, bq2, nullptr, q2a, 80, 160, 1600);
    conv_kernel<1, false, false, float><<<dim3(13, 3, 32), 256, 0, stream>>>(q2a, Wq3, bq3, nullptr, qfv, 80, 80, 1600);
    sqsum_kernel<<<dim3(7, 32), 256, 0, stream>>>(qfv, q2s, 80, 1600);
    transpose_cast_kernel<true><<<dim3(25, 32), 256, 0, stream>>>(qfv, q2s, qT, 1600);
    // fused attention (MFMA)
    attn_mfma_kernel<<<dim3(25, 32), 256, 0, stream>>>(qT, kT, mask, prior, attn_out, lp_out);
}

// Round 5
// 603.844 us; speedup vs baseline: 3.4011x; 1.6248x over previous
//
#include <hip/hip_runtime.h>
#include <math.h>

#define TEMP 0.0005f
#define B_    32
#define CMEL  80
#define CTXT  512
#define T1_   1600
#define T2_   400

typedef short short8 __attribute__((ext_vector_type(8)));
typedef float f32x4 __attribute__((ext_vector_type(4)));

__device__ inline unsigned short f2bf(float f) {
    unsigned u = __float_as_uint(f);
    u += 0x7FFF + ((u >> 16) & 1);
    return (unsigned short)(u >> 16);
}
__device__ inline unsigned pack2(float a, float b) {
    return (unsigned)f2bf(a) | ((unsigned)f2bf(b) << 16);
}

// ---------------- speaker-embed bias vectors ----------------
__global__ void bias_kernel(const float* __restrict__ se,
                            const float* __restrict__ Wks, const float* __restrict__ bks,
                            const float* __restrict__ Wqs, const float* __restrict__ bqs,
                            float* __restrict__ kb, float* __restrict__ qb) {
    int tid = blockIdx.x * blockDim.x + threadIdx.x;
    const int nk = B_ * CTXT;
    if (tid < nk) {
        int b = tid / CTXT, c = tid % CTXT;
        const float4* s4 = reinterpret_cast<const float4*>(se + b * CTXT);
        const float4* w4 = reinterpret_cast<const float4*>(Wks + (size_t)c * CTXT);
        float acc = bks[c];
        #pragma unroll 4
        for (int j = 0; j < CTXT / 4; ++j) {
            float4 a = s4[j], w = w4[j];
            acc += a.x * w.x + a.y * w.y + a.z * w.z + a.w * w.w;
        }
        kb[tid] = acc;
    } else if (tid < nk + B_ * CMEL) {
        int t = tid - nk;
        int b = t / CMEL, c = t % CMEL;
        const float4* s4 = reinterpret_cast<const float4*>(se + b * CTXT);
        const float4* w4 = reinterpret_cast<const float4*>(Wqs + (size_t)c * CTXT);
        float acc = bqs[c];
        #pragma unroll 4
        for (int j = 0; j < CTXT / 4; ++j) {
            float4 a = s4[j], w = w4[j];
            acc += a.x * w.x + a.y * w.y + a.z * w.z + a.w * w.w;
        }
        qb[t] = acc;
    }
}

// ---------------- all weight casts in one launch ----------------
// Ab1[1024][1536] (dt*512+ci) | A2[80][1024] | A3[160][288] (dt*96+cc, pad) |
// A4[80][160] | A5[80][96] (pad)
__global__ void cast_weights_kernel(
        const float* __restrict__ Wk1, const float* __restrict__ Wk2,
        const float* __restrict__ Wq1, const float* __restrict__ Wq2,
        const float* __restrict__ Wq3,
        unsigned short* __restrict__ Ab1, unsigned short* __restrict__ A2,
        unsigned short* __restrict__ A3, unsigned short* __restrict__ A4,
        unsigned short* __restrict__ A5) {
    int e = blockIdx.x * 256 + threadIdx.x;
    const int n1 = 1572864, n2 = 81920, n3 = 46080, n4 = 12800, n5 = 7680;
    if (e < n1) {
        int co = e / 1536, rem = e - co * 1536;
        int dt = rem >> 9, ci = rem & 511;
        Ab1[e] = f2bf(Wk1[((size_t)co * 512 + ci) * 3 + dt]);
    } else if ((e -= n1) < n2) {
        A2[e] = f2bf(Wk2[e]);
    } else if ((e -= n2) < n3) {
        int co = e / 288, rem = e - co * 288;
        int dt = rem / 96, cc = rem - dt * 96;
        A3[e] = (cc < 80) ? f2bf(Wq1[((size_t)co * 80 + cc) * 3 + dt]) : 0;
    } else if ((e -= n3) < n4) {
        A4[e] = f2bf(Wq2[e]);
    } else if ((e -= n4) < n5) {
        int co = e / 96, cc = e - co * 96;
        A5[e] = (cc < 80) ? f2bf(Wq3[co * 80 + cc]) : 0;
    }
}

// ---------------- cast keys+bias -> Xk[b][t+1][512] bf16 (transposed, padded rows) ----
__global__ void castXk_kernel(const float* __restrict__ keys, const float* __restrict__ kb,
                              unsigned short* __restrict__ Xt) {
    __shared__ float tile[64][65];
    const int b = blockIdx.z;
    const int row0 = blockIdx.x * 64;
    const int ci0 = blockIdx.y * 64;
    const int tid = threadIdx.x;
    #pragma unroll
    for (int i = 0; i < 16; ++i) {
        int linear = i * 256 + tid;
        int ci_l = linear >> 6, t_l = linear & 63;
        int t = row0 + t_l - 1;
        float v = 0.f;
        if (t >= 0 && t < 400)
            v = keys[((size_t)b * 512 + ci0 + ci_l) * 400 + t] + kb[b * 512 + ci0 + ci_l];
        tile[t_l][ci_l] = v;
    }
    __syncthreads();
    #pragma unroll
    for (int i = 0; i < 16; ++i) {
        int linear = i * 256 + tid;
        int t_l = linear >> 6, ci_l = linear & 63;
        int row = row0 + t_l;
        if (row < 456)
            Xt[((size_t)b * 456 + row) * 512 + ci0 + ci_l] = f2bf(tile[t_l][ci_l]);
    }
}

// ---------------- cast queries+bias -> Xq1[b][t+1][96] bf16 (transposed, halo+ch pad) ----
__global__ __launch_bounds__(256) void castXq_kernel(
        const float* __restrict__ q, const float* __restrict__ qb,
        unsigned short* __restrict__ Xq1) {
    __shared__ float tile[80][65];
    const int b = blockIdx.y;
    const int t0 = blockIdx.x * 64;
    const int tid = threadIdx.x;
    // halo rows
    if (t0 == 0 && tid < 48)
        ((unsigned*)(Xq1 + (size_t)b * 1602 * 96))[tid] = 0u;
    if (t0 == 1536 && tid < 48)
        ((unsigned*)(Xq1 + ((size_t)b * 1602 + 1601) * 96))[tid] = 0u;
    {
        int tl = tid & 63, c0 = tid >> 6;
        for (int c = c0; c < 80; c += 4)
            tile[c][tl] = q[((size_t)b * 80 + c) * 1600 + t0 + tl] + qb[b * 80 + c];
    }
    __syncthreads();
    int row = tid >> 2, cg = tid & 3;
    int t = t0 + row;
    unsigned* orow = (unsigned*)(Xq1 + ((size_t)b * 1602 + t + 1) * 96 + cg * 24);
    #pragma unroll
    for (int jj = 0; jj < 12; ++jj) {
        int c0 = cg * 24 + jj * 2, c1 = c0 + 1;
        float f0 = (c0 < 80) ? tile[c0][row] : 0.f;
        float f1 = (c1 < 80) ? tile[c1][row] : 0.f;
        orow[jj] = pack2(f0, f1);
    }
}

// ---------------- keys conv1 via bf16 MFMA -> channel-last k1c[b][t][1024] ----------------
__global__ __launch_bounds__(256) void conv1k_mfma(
        const unsigned short* __restrict__ Ab, const unsigned short* __restrict__ Xt,
        const float* __restrict__ bias, unsigned short* __restrict__ k1c) {
    __shared__ short As[3 * 128 * 40];
    __shared__ short Xs[66 * 40];
    const int b = blockIdx.z;
    const int co0 = blockIdx.y * 128;
    const int t0 = blockIdx.x * 64;
    const int tid = threadIdx.x;
    const int lane = tid & 63, w = tid >> 6;
    const int wm = w >> 1, wn = w & 1;
    const int l15 = lane & 15, quad = lane >> 4;
    f32x4 acc[4][2];
    #pragma unroll
    for (int mt = 0; mt < 4; ++mt)
        #pragma unroll
        for (int nt = 0; nt < 2; ++nt)
            acc[mt][nt] = (f32x4){0.f, 0.f, 0.f, 0.f};

    for (int ci0 = 0; ci0 < 512; ci0 += 32) {
        __syncthreads();
        #pragma unroll
        for (int i = 0; i < 6; ++i) {
            int linear = i * 256 + tid;
            int dt = linear >> 9;
            int rem = linear & 511;
            int r = rem >> 2, c16 = rem & 3;
            int4 v = *(const int4*)(Ab + (size_t)(co0 + r) * 1536 + dt * 512 + ci0 + c16 * 8);
            *(int4*)(As + (dt * 128 + r) * 40 + c16 * 8) = v;
        }
        #pragma unroll
        for (int i = 0; i < 2; ++i) {
            int c = i * 256 + tid;
            if (c < 264) {
                int row = c >> 2, c16 = c & 3;
                int4 v = *(const int4*)(Xt + ((size_t)b * 456 + t0 + row) * 512 + ci0 + c16 * 8);
                *(int4*)(Xs + row * 40 + c16 * 8) = v;
            }
        }
        __syncthreads();
        #pragma unroll
        for (int dt = 0; dt < 3; ++dt) {
            short8 af[4], bfr[2];
            #pragma unroll
            for (int mt = 0; mt < 4; ++mt)
                af[mt] = *(const short8*)(As + (dt * 128 + wm * 64 + mt * 16 + l15) * 40 + quad * 8);
            #pragma unroll
            for (int nt = 0; nt < 2; ++nt)
                bfr[nt] = *(const short8*)(Xs + (wn * 32 + nt * 16 + l15 + dt) * 40 + quad * 8);
            #pragma unroll
            for (int mt = 0; mt < 4; ++mt)
                #pragma unroll
                for (int nt = 0; nt < 2; ++nt)
                    acc[mt][nt] = __builtin_amdgcn_mfma_f32_16x16x32_bf16(af[mt], bfr[nt], acc[mt][nt], 0, 0, 0);
        }
    }
    // epilogue: row = co = quad*4+r, col = t = l15 -> channel-last 8B packed stores
    #pragma unroll
    for (int mt = 0; mt < 4; ++mt) {
        int cob = co0 + wm * 64 + mt * 16 + quad * 4;
        float bv[4];
        #pragma unroll
        for (int r = 0; r < 4; ++r) bv[r] = bias[cob + r];
        #pragma unroll
        for (int nt = 0; nt < 2; ++nt) {
            int t = t0 + wn * 32 + nt * 16 + l15;
            if (t >= 400) continue;
            float v0 = fmaxf(acc[mt][nt][0] + bv[0], 0.f);
            float v1 = fmaxf(acc[mt][nt][1] + bv[1], 0.f);
            float v2 = fmaxf(acc[mt][nt][2] + bv[2], 0.f);
            float v3 = fmaxf(acc[mt][nt][3] + bv[3], 0.f);
            uint2 p;
            p.x = pack2(v0, v1);
            p.y = pack2(v2, v3);
            *(uint2*)(k1c + ((size_t)b * 400 + t) * 1024 + cob) = p;
        }
    }
}

// ---------------- generic channel-last 1x1(/k3) conv GEMM via MFMA, no LDS ----------------
// A[M][NKC*32] bf16 (M = MT*16), X[b][NR][INW] bf16 K-contiguous rows.
// OMODE: 0 plain (OUTW), 1 plain + zero ch 80..95 (OUTW=96),
//        2 kT epilogue (e80=-0.5*ss, e81=1), 3 qT epilogue (e80=1, e81=-0.5*ss).
// DTC>0: K is dt-segmented (k=3 conv); B row = s + dt, chunk offset within row.
template<int MT, int NKC, int DTC, bool RELU, int OMODE, int INW, int OUTW, int N, int NR>
__global__ __launch_bounds__(256) void gemm_cl(
        const unsigned short* __restrict__ A, const unsigned short* __restrict__ X,
        const float* __restrict__ bias, unsigned short* __restrict__ out) {
    const int b = blockIdx.y;
    const int tid = threadIdx.x;
    const int lane = tid & 63, w = tid >> 6;
    const int l15 = lane & 15, quad = lane >> 4;
    const int s = blockIdx.x * 64 + w * 16 + l15;
    const int srow = (s < N) ? s : (N - 1);
    const unsigned short* xb = X + (size_t)b * NR * INW;

    f32x4 acc[MT];
    #pragma unroll
    for (int mt = 0; mt < MT; ++mt) acc[mt] = (f32x4){0.f, 0.f, 0.f, 0.f};

    #pragma unroll
    for (int kc = 0; kc < NKC; ++kc) {
        const int dt = DTC ? (kc / DTC) : 0;
        const int koff = DTC ? ((kc - dt * DTC) * 32) : (kc * 32);
        short8 bfr = *(const short8*)(xb + (size_t)(srow + dt) * INW + koff + quad * 8);
        #pragma unroll
        for (int mt = 0; mt < MT; ++mt) {
            short8 af = *(const short8*)(A + (size_t)(mt * 16 + l15) * (NKC * 32) + kc * 32 + quad * 8);
            acc[mt] = __builtin_amdgcn_mfma_f32_16x16x32_bf16(af, bfr, acc[mt], 0, 0, 0);
        }
    }
    if (s >= N) return;  // wave-uniform (N % 16 == 0)

    float v[MT][4];
    float ss = 0.f;
    #pragma unroll
    for (int mt = 0; mt < MT; ++mt) {
        #pragma unroll
        for (int r = 0; r < 4; ++r) {
            float x = acc[mt][r] + bias[mt * 16 + quad * 4 + r];
            if (RELU) x = fmaxf(x, 0.f);
            v[mt][r] = x;
            if (OMODE >= 2) ss += x * x;
        }
    }
    if (OMODE >= 2) {
        ss += __shfl_xor(ss, 16, 64);
        ss += __shfl_xor(ss, 32, 64);
    }
    unsigned short* orow = out + ((size_t)b * N + s) * OUTW;
    #pragma unroll
    for (int mt = 0; mt < MT; ++mt) {
        uint2 p;
        p.x = pack2(v[mt][0], v[mt][1]);
        p.y = pack2(v[mt][2], v[mt][3]);
        *(uint2*)(orow + mt * 16 + quad * 4) = p;
    }
    if (OMODE == 1 && quad == 0) {
        uint4 z = {0u, 0u, 0u, 0u};
        *(uint4*)(orow + 80) = z;
        *(uint4*)(orow + 88) = z;
    }
    if (OMODE >= 2 && quad == 0) {
        float e80 = (OMODE == 2) ? (-0.5f * ss) : 1.0f;
        float e81 = (OMODE == 2) ? 1.0f : (-0.5f * ss);
        uint4 z0 = {pack2(e80, e81), 0u, 0u, 0u};
        uint4 z1 = {0u, 0u, 0u, 0u};
        *(uint4*)(orow + 80) = z0;
        *(uint4*)(orow + 88) = z1;
    }
}

// ---------------- fused qk MFMA + log_softmax + prior + masked softmax ----------------
__global__ __launch_bounds__(256) void attn_mfma_kernel(
        const unsigned short* __restrict__ qT, const unsigned short* __restrict__ kT,
        const int* __restrict__ mask, const float* __restrict__ prior,
        float* __restrict__ attn_out, float* __restrict__ lp_out) {
    __shared__ float msh[400];
    const int b = blockIdx.y;
    const int t10 = blockIdx.x * 64;
    const int tid = threadIdx.x;
    const int lane = tid & 63, w = tid >> 6;
    const int l15 = lane & 15, quad = lane >> 4;
    for (int s = tid; s < 400; s += 256)
        msh[s] = mask[b * T2_ + s] ? 1.f : 0.f;
    __syncthreads();

    const unsigned short* qrow = qT + ((size_t)b * T1_ + t10 + w * 16 + l15) * 96;
    short8 af[3];
    #pragma unroll
    for (int kc = 0; kc < 3; ++kc)
        af[kc] = *(const short8*)(qrow + kc * 32 + quad * 8);

    f32x4 acc[25];
    #pragma unroll
    for (int ns = 0; ns < 25; ++ns) acc[ns] = (f32x4){0.f, 0.f, 0.f, 0.f};
    const unsigned short* kbase = kT + (size_t)b * T2_ * 96 + l15 * 96 + quad * 8;
    #pragma unroll
    for (int ns = 0; ns < 25; ++ns) {
        #pragma unroll
        for (int kc = 0; kc < 3; ++kc) {
            short8 bf = *(const short8*)(kbase + ns * 16 * 96 + kc * 32);
            acc[ns] = __builtin_amdgcn_mfma_f32_16x16x32_bf16(af[kc], bf, acc[ns], 0, 0, 0);
        }
    }

    const float NEG = -INFINITY;
    const float K2T = 2.0f * TEMP;
    #pragma unroll
    for (int r = 0; r < 4; ++r) {
        const int t1 = t10 + w * 16 + quad * 4 + r;
        float l[25];
        #pragma unroll
        for (int ns = 0; ns < 25; ++ns) l[ns] = K2T * acc[ns][r];
        float m = l[0];
        #pragma unroll
        for (int ns = 1; ns < 25; ++ns) m = fmaxf(m, l[ns]);
        #pragma unroll
        for (int off = 1; off <= 8; off <<= 1) m = fmaxf(m, __shfl_xor(m, off, 16));
        float sum = 0.f;
        #pragma unroll
        for (int ns = 0; ns < 25; ++ns) sum += __expf(l[ns] - m);
        #pragma unroll
        for (int off = 1; off <= 8; off <<= 1) sum += __shfl_xor(sum, off, 16);
        const float lse = m + __logf(sum);

        const float* prow = prior + ((size_t)b * T1_ + t1) * T2_;
        float* lpr = lp_out + ((size_t)b * T1_ + t1) * T2_;
        float* atr = attn_out + ((size_t)b * T1_ + t1) * T2_;
        #pragma unroll
        for (int ns = 0; ns < 25; ++ns) {
            int s = ns * 16 + l15;
            float lp = l[ns] - lse + __logf(prow[s] + 1e-8f);
            lpr[s] = lp;
            l[ns] = (msh[s] != 0.f) ? NEG : lp;
        }
        float m2 = NEG;
        #pragma unroll
        for (int ns = 0; ns < 25; ++ns) m2 = fmaxf(m2, l[ns]);
        #pragma unroll
        for (int off = 1; off <= 8; off <<= 1) m2 = fmaxf(m2, __shfl_xor(m2, off, 16));
        float s2 = 0.f;
        #pragma unroll
        for (int ns = 0; ns < 25; ++ns) { float e = __expf(l[ns] - m2); s2 += e; l[ns] = e; }
        #pragma unroll
        for (int off = 1; off <= 8; off <<= 1) s2 += __shfl_xor(s2, off, 16);
        const float inv = 1.f / s2;
        #pragma unroll
        for (int ns = 0; ns < 25; ++ns) atr[ns * 16 + l15] = l[ns] * inv;
    }
}

extern "C" void kernel_launch(void* const* d_in, const int* in_sizes, int n_in,
                              void* d_out, int out_size, void* d_ws, size_t ws_size,
                              hipStream_t stream) {
    const float* queries = (const float*)d_in[0];
    const float* keys    = (const float*)d_in[1];
    const int*   mask    = (const int*)d_in[2];
    const float* prior   = (const float*)d_in[3];
    const float* se      = (const float*)d_in[4];
    const float* Wk1 = (const float*)d_in[5];
    const float* bk1 = (const float*)d_in[6];
    const float* Wk2 = (const float*)d_in[7];
    const float* bk2 = (const float*)d_in[8];
    const float* Wq1 = (const float*)d_in[9];
    const float* bq1 = (const float*)d_in[10];
    const float* Wq2 = (const float*)d_in[11];
    const float* bq2 = (const float*)d_in[12];
    const float* Wq3 = (const float*)d_in[13];
    const float* bq3 = (const float*)d_in[14];
    const float* Wks = (const float*)d_in[15];
    const float* bks = (const float*)d_in[16];
    const float* Wqs = (const float*)d_in[17];
    const float* bqs = (const float*)d_in[18];

    // workspace (float units), peak 14,240,768 fl = 57.0 MB:
    // kb 0 | qb 16,384 | Ab1 18,944 | A2 805,376 | A3 846,336 | A4 869,376 | A5 875,776
    // qT 879,616 | kT 3,337,216 | D = 3,951,616
    // keys: Xk @D (3,735,552) | k1c @D+3,735,552 (6,553,600)
    // q:    Xq1 @D (2,460,672) | Xq2 @D+2,460,672 (4,096,000) | Xq3 @D (overlays dead Xq1)
    float* ws = (float*)d_ws;
    float* kb = ws;
    float* qb = ws + 16384;
    unsigned short* Ab1 = (unsigned short*)(ws + 18944);
    unsigned short* A2  = (unsigned short*)(ws + 805376);
    unsigned short* A3  = (unsigned short*)(ws + 846336);
    unsigned short* A4  = (unsigned short*)(ws + 869376);
    unsigned short* A5  = (unsigned short*)(ws + 875776);
    unsigned short* qT  = (unsigned short*)(ws + 879616);
    unsigned short* kT  = (unsigned short*)(ws + 3337216);
    const size_t D = 3951616;
    unsigned short* Xk  = (unsigned short*)(ws + D);
    unsigned short* k1c = (unsigned short*)(ws + D + 3735552);
    unsigned short* Xq1 = (unsigned short*)(ws + D);
    unsigned short* Xq2 = (unsigned short*)(ws + D + 2460672);
    unsigned short* Xq3 = (unsigned short*)(ws + D);

    float* attn_out = (float*)d_out;
    float* lp_out   = attn_out + (size_t)B_ * T1_ * T2_;

    bias_kernel<<<dim3(74), dim3(256), 0, stream>>>(se, Wks, bks, Wqs, bqs, kb, qb);
    cast_weights_kernel<<<dim3(6724), dim3(256), 0, stream>>>(Wk1, Wk2, Wq1, Wq2, Wq3,
                                                              Ab1, A2, A3, A4, A5);
    // keys path
    castXk_kernel<<<dim3(8, 8, 32), dim3(256), 0, stream>>>(keys, kb, Xk);
    conv1k_mfma<<<dim3(7, 8, 32), dim3(256), 0, stream>>>(Ab1, Xk, bk1, k1c);
    gemm_cl<5, 32, 0, false, 2, 1024, 96, 400, 400>
        <<<dim3(7, 32), 256, 0, stream>>>(A2, k1c, bk2, kT);
    // query path
    castXq_kernel<<<dim3(25, 32), dim3(256), 0, stream>>>(queries, qb, Xq1);
    gemm_cl<10, 9, 3, true, 0, 96, 160, 1600, 1602>
        <<<dim3(25, 32), 256, 0, stream>>>(A3, Xq1, bq1, Xq2);
    gemm_cl<5, 5, 0, true, 1, 160, 96, 1600, 1600>
        <<<dim3(25, 32), 256, 0, stream>>>(A4, Xq2, bq2, Xq3);
    gemm_cl<5, 3, 0, false, 3, 96, 96, 1600, 1600>
        <<<dim3(25, 32), 256, 0, stream>>>(A5, Xq3, bq3, qT);
    // fused attention
    attn_mfma_kernel<<<dim3(25, 32), 256, 0, stream>>>(qT, kT, mask, prior, attn_out, lp_out);
}